// Round 1
// baseline (7324.760 us; speedup 1.0000x reference)
//
#include <hip/hip_runtime.h>
#include <hip/hip_bf16.h>

#define D 128
#define EPS 1e-5f

typedef __attribute__((ext_vector_type(4))) float fx4;
typedef __attribute__((ext_vector_type(8))) short bfx8;
typedef __attribute__((ext_vector_type(4))) short bfx4;

__device__ __forceinline__ short f2bf(float f){
  unsigned u = __builtin_bit_cast(unsigned, f);
  unsigned r = (u + 0x7fffu + ((u >> 16) & 1u)) >> 16;
  return (short)(unsigned short)r;
}
__device__ __forceinline__ float bf2f(short s){
  unsigned u = ((unsigned)(unsigned short)s) << 16;
  return __builtin_bit_cast(float, u);
}
// byte offset into swizzled bf16 A-tile [128 rows][128 k]
__device__ __forceinline__ int swzofs(int r, int k){
  return ((r << 8) + (k << 1)) ^ ((r & 7) << 4);
}

// ---------------- weight prep: 5 transposed bf16 128x128 blocks ----------------
// WT[m][n][k] = srcm[k*128+n]; m: 0=We1 1=Wn1a 2=We2 3=Wn1b 4=Wn2a
__global__ void prep_w(const float* __restrict__ We, const float* __restrict__ Wn1,
                       const float* __restrict__ Wn2, short* __restrict__ WT){
  int o = blockIdx.x * 256 + threadIdx.x;            // 81920 total
  int m = o >> 14; int rem = o & 16383;
  int k = rem >> 7; int n = rem & 127;
  const float* src;
  switch (m){
    case 0: src = We; break;
    case 1: src = Wn1; break;
    case 2: src = We + 128*128; break;
    case 3: src = Wn1 + 128*128; break;
    default: src = Wn2; break;
  }
  WT[m*16384 + n*128 + k] = f2bf(src[k*128 + n]);
}

// U1 = u @ We[256:384], U2 = u @ Wn2[128:256]   (f32, 32x128 each)
__global__ void prep_u(const float* __restrict__ u, const float* __restrict__ We,
                       const float* __restrict__ Wn2, float* __restrict__ U1,
                       float* __restrict__ U2){
  int o = blockIdx.x * 256 + threadIdx.x;            // 8192
  int which = o >> 12; int rem = o & 4095;
  int g = rem >> 7; int j = rem & 127;
  const float* W = which ? (Wn2 + 128*128) : (We + 256*128);
  float s = 0.f;
  for (int k = 0; k < 128; ++k) s += u[g*128 + k] * W[k*128 + j];
  (which ? U2 : U1)[rem] = s;
}

__global__ void counts_k(const int* __restrict__ erow, const int* __restrict__ batch,
                         int* ncnt, int* gcnt, int nE, int nN){
  int i = blockIdx.x * 256 + threadIdx.x;
  if (i < nE) atomicAdd(ncnt + erow[i], 1);
  else if (i - nE < nN) atomicAdd(gcnt + batch[i - nE], 1);
}

__global__ void bn_fin(const float* __restrict__ s, const float* __restrict__ q,
                       const float* __restrict__ gamma, const float* __restrict__ beta,
                       float cnt, float* __restrict__ out){
  int j = threadIdx.x;
  float m = s[j] / cnt;
  float v = q[j] / cnt - m*m;
  float sc = gamma[j] * rsqrtf(v + EPS);
  out[j] = sc;
  out[128 + j] = beta[j] - m*sc;
}

// ---------------- P/Q precompute GEMM: Out(bf16, Mx128) = X(f32) @ Wt^T ----------------
__global__ __launch_bounds__(256, 2) void gemm_xw(const float* __restrict__ X,
                                                  const short* __restrict__ Wt,
                                                  short* __restrict__ Out, int M){
  __shared__ __align__(16) char lds[64*132*4 + 1024];
  float* Vt = (float*)lds;
  const int t = threadIdx.x;
  const int nb = blockIdx.x * 128;

  #pragma unroll
  for (int i = 0; i < 16; ++i){
    int foff = (t + 256*i) * 4;
    int r = foff >> 7, k = foff & 127;
    int n = nb + r;
    fx4 v = {0.f,0.f,0.f,0.f};
    if (n < M) v = *reinterpret_cast<const fx4*>(X + (size_t)n*D + k);
    bfx4 bv;
    #pragma unroll
    for (int j = 0; j < 4; ++j) bv[j] = f2bf(v[j]);
    *reinterpret_cast<bfx4*>(lds + swzofs(r, k)) = bv;
  }

  const int lane = t & 63, wid = t >> 6;
  const int wr = wid >> 1, wc = wid & 1;
  const int lr = lane & 15, lh = lane >> 4;
  bfx8 bfr[4][4];
  #pragma unroll
  for (int n = 0; n < 4; ++n)
    #pragma unroll
    for (int s = 0; s < 4; ++s)
      bfr[n][s] = *reinterpret_cast<const bfx8*>(Wt + ((wc*64 + n*16 + lr)*D + s*32 + lh*8));

  fx4 acc[4][4];
  #pragma unroll
  for (int m = 0; m < 4; ++m)
    #pragma unroll
    for (int n = 0; n < 4; ++n) acc[m][n] = (fx4){0.f,0.f,0.f,0.f};

  __syncthreads();
  #pragma unroll
  for (int m = 0; m < 4; ++m){
    int row = wr*64 + m*16 + lr;
    bfx8 af[4];
    #pragma unroll
    for (int s = 0; s < 4; ++s)
      af[s] = *reinterpret_cast<const bfx8*>(lds + swzofs(row, s*32 + lh*8));
    #pragma unroll
    for (int n = 0; n < 4; ++n)
      #pragma unroll
      for (int s = 0; s < 4; ++s)
        acc[m][n] = __builtin_amdgcn_mfma_f32_16x16x32_bf16(af[s], bfr[n][s], acc[m][n], 0, 0, 0);
  }
  __syncthreads();

  for (int h = 0; h < 2; ++h){
    if (wr == h){
      #pragma unroll
      for (int m = 0; m < 4; ++m)
        #pragma unroll
        for (int n = 0; n < 4; ++n)
          #pragma unroll
          for (int i = 0; i < 4; ++i)
            Vt[(m*16 + lh*4 + i)*132 + wc*64 + n*16 + lr] = acc[m][n][i];
    }
    __syncthreads();
    int r = t & 63, ch = t >> 6;
    int n = nb + h*64 + r;
    if (n < M){
      #pragma unroll
      for (int i = 0; i < 8; ++i){
        int c = ch*32 + i*4;
        fx4 v = *reinterpret_cast<const fx4*>(&Vt[r*132 + c]);
        bfx4 o;
        #pragma unroll
        for (int j = 0; j < 4; ++j) o[j] = f2bf(v[j]);
        *reinterpret_cast<bfx4*>(Out + (size_t)n*D + c) = o;
      }
    }
    __syncthreads();
  }
}

// ---------------- edge passes ----------------
// MODE 0: v = eatt@We2t + 0.5(P[row]+P[col]) + U1[batch[row]]; store v -> eio; stats_e
// MODE 1: eo = prelu(bn(v)) at staging (write back); h = eo@Wn1bt + Q[col]; stats_n1
// MODE 2: h = eo@Wn1bt + Q[col]; h' = prelu(bn(h)); atomicAdd agg[row] += h'
template<int MODE>
__global__ __launch_bounds__(256, 2) void edge_pass(
    const float* __restrict__ Asrc, float* eio,
    const int* __restrict__ erow, const int* __restrict__ ecol,
    const int* __restrict__ batch, const short* __restrict__ PQ,
    const float* __restrict__ U1, const short* __restrict__ Wt,
    const float* __restrict__ a_ss, const float* __restrict__ a_alpha,
    const float* __restrict__ o_ss, const float* __restrict__ o_alpha,
    float* __restrict__ stat_sum, float* __restrict__ stat_ssq,
    float* __restrict__ agg, int nE)
{
  __shared__ __align__(16) char lds[64*132*4 + 1024];
  float* Vt = (float*)lds;
  float* lsum = (float*)(lds + 64*132*4);
  float* lssq = lsum + 128;

  const int t = threadIdx.x;
  const int eb = blockIdx.x * 128;
  if (MODE != 2 && t < 128){ lsum[t] = 0.f; lssq[t] = 0.f; }

  const float* src = (MODE == 0) ? Asrc : eio;
  const float aal = (MODE == 1) ? *a_alpha : 0.f;

  #pragma unroll
  for (int i = 0; i < 16; ++i){
    int foff = (t + 256*i) * 4;
    int r = foff >> 7, k = foff & 127;
    int e = eb + r;
    fx4 v = {0.f,0.f,0.f,0.f};
    if (e < nE) v = *reinterpret_cast<const fx4*>(src + (size_t)e*D + k);
    if (MODE == 1){
      fx4 s4 = *reinterpret_cast<const fx4*>(a_ss + k);
      fx4 b4 = *reinterpret_cast<const fx4*>(a_ss + 128 + k);
      #pragma unroll
      for (int j = 0; j < 4; ++j){
        float hh = v[j]*s4[j] + b4[j];
        v[j] = hh >= 0.f ? hh : aal*hh;
      }
      if (e < nE) *reinterpret_cast<fx4*>(eio + (size_t)e*D + k) = v;
    }
    bfx4 bv;
    #pragma unroll
    for (int j = 0; j < 4; ++j) bv[j] = f2bf(v[j]);
    *reinterpret_cast<bfx4*>(lds + swzofs(r, k)) = bv;
  }

  const int lane = t & 63, wid = t >> 6;
  const int wr = wid >> 1, wc = wid & 1;
  const int lr = lane & 15, lh = lane >> 4;
  bfx8 bfr[4][4];
  #pragma unroll
  for (int n = 0; n < 4; ++n)
    #pragma unroll
    for (int s = 0; s < 4; ++s)
      bfr[n][s] = *reinterpret_cast<const bfx8*>(Wt + ((wc*64 + n*16 + lr)*D + s*32 + lh*8));

  fx4 acc[4][4];
  #pragma unroll
  for (int m = 0; m < 4; ++m)
    #pragma unroll
    for (int n = 0; n < 4; ++n) acc[m][n] = (fx4){0.f,0.f,0.f,0.f};

  __syncthreads();
  #pragma unroll
  for (int m = 0; m < 4; ++m){
    int row = wr*64 + m*16 + lr;
    bfx8 af[4];
    #pragma unroll
    for (int s = 0; s < 4; ++s)
      af[s] = *reinterpret_cast<const bfx8*>(lds + swzofs(row, s*32 + lh*8));
    #pragma unroll
    for (int n = 0; n < 4; ++n)
      #pragma unroll
      for (int s = 0; s < 4; ++s)
        acc[m][n] = __builtin_amdgcn_mfma_f32_16x16x32_bf16(af[s], bfr[n][s], acc[m][n], 0, 0, 0);
  }
  __syncthreads();

  const float oal = (MODE == 2) ? *o_alpha : 0.f;

  for (int h = 0; h < 2; ++h){
    if (wr == h){
      #pragma unroll
      for (int m = 0; m < 4; ++m)
        #pragma unroll
        for (int n = 0; n < 4; ++n)
          #pragma unroll
          for (int i = 0; i < 4; ++i)
            Vt[(m*16 + lh*4 + i)*132 + wc*64 + n*16 + lr] = acc[m][n][i];
    }
    __syncthreads();
    {
      int r = t & 63, ch = t >> 6;
      int e = eb + h*64 + r;
      bool valid = e < nE;
      int re = 0, ce = 0, g = 0;
      if (valid){
        re = erow[e];
        ce = ecol[e];
        if (MODE == 0) g = batch[re];
      }
      #pragma unroll
      for (int i = 0; i < 8; ++i){
        int c = ch*32 + i*4;
        fx4 v = *reinterpret_cast<const fx4*>(&Vt[r*132 + c]);
        if (valid){
          if (MODE == 0){
            bfx4 pr = *reinterpret_cast<const bfx4*>(PQ + (size_t)re*D + c);
            bfx4 pc = *reinterpret_cast<const bfx4*>(PQ + (size_t)ce*D + c);
            fx4 u4 = *reinterpret_cast<const fx4*>(U1 + g*D + c);
            #pragma unroll
            for (int j = 0; j < 4; ++j){
              float vv = v[j] + 0.5f*(bf2f(pr[j]) + bf2f(pc[j])) + u4[j];
              v[j] = vv;
              atomicAdd(&lsum[c+j], vv);
              atomicAdd(&lssq[c+j], vv*vv);
            }
            *reinterpret_cast<fx4*>(eio + (size_t)e*D + c) = v;
          } else if (MODE == 1){
            bfx4 q = *reinterpret_cast<const bfx4*>(PQ + (size_t)ce*D + c);
            #pragma unroll
            for (int j = 0; j < 4; ++j){
              float hh = v[j] + bf2f(q[j]);
              atomicAdd(&lsum[c+j], hh);
              atomicAdd(&lssq[c+j], hh*hh);
            }
          } else {
            bfx4 q = *reinterpret_cast<const bfx4*>(PQ + (size_t)ce*D + c);
            fx4 s4 = *reinterpret_cast<const fx4*>(o_ss + c);
            fx4 b4 = *reinterpret_cast<const fx4*>(o_ss + 128 + c);
            #pragma unroll
            for (int j = 0; j < 4; ++j){
              float hh = v[j] + bf2f(q[j]);
              hh = hh*s4[j] + b4[j];
              hh = hh >= 0.f ? hh : oal*hh;
              atomicAdd(agg + (size_t)re*D + c + j, hh);
            }
          }
        }
      }
    }
    __syncthreads();
  }

  if (MODE != 2){
    if (t < 128){
      atomicAdd(stat_sum + t, lsum[t]);
      atomicAdd(stat_ssq + t, lssq[t]);
    }
  }
}

// ---------------- node layer 2 GEMM: xpre = (agg/cnt)@Wn2at + U2[batch]; stats_n2 ----------------
__global__ __launch_bounds__(256, 2) void node2_pass(
    const float* __restrict__ agg, const int* __restrict__ ncnt,
    const int* __restrict__ batch, const float* __restrict__ U2,
    const short* __restrict__ Wt, float* __restrict__ Xout,
    float* __restrict__ stat_sum, float* __restrict__ stat_ssq, int M)
{
  __shared__ __align__(16) char lds[64*132*4 + 1024];
  float* Vt = (float*)lds;
  float* lsum = (float*)(lds + 64*132*4);
  float* lssq = lsum + 128;

  const int t = threadIdx.x;
  const int nb = blockIdx.x * 128;
  if (t < 128){ lsum[t] = 0.f; lssq[t] = 0.f; }

  #pragma unroll
  for (int i = 0; i < 16; ++i){
    int foff = (t + 256*i) * 4;
    int r = foff >> 7, k = foff & 127;
    int n = nb + r;
    fx4 v = {0.f,0.f,0.f,0.f};
    if (n < M){
      v = *reinterpret_cast<const fx4*>(agg + (size_t)n*D + k);
      float inv = 1.f / fmaxf((float)ncnt[n], 1.f);
      #pragma unroll
      for (int j = 0; j < 4; ++j) v[j] *= inv;
    }
    bfx4 bv;
    #pragma unroll
    for (int j = 0; j < 4; ++j) bv[j] = f2bf(v[j]);
    *reinterpret_cast<bfx4*>(lds + swzofs(r, k)) = bv;
  }

  const int lane = t & 63, wid = t >> 6;
  const int wr = wid >> 1, wc = wid & 1;
  const int lr = lane & 15, lh = lane >> 4;
  bfx8 bfr[4][4];
  #pragma unroll
  for (int n = 0; n < 4; ++n)
    #pragma unroll
    for (int s = 0; s < 4; ++s)
      bfr[n][s] = *reinterpret_cast<const bfx8*>(Wt + ((wc*64 + n*16 + lr)*D + s*32 + lh*8));

  fx4 acc[4][4];
  #pragma unroll
  for (int m = 0; m < 4; ++m)
    #pragma unroll
    for (int n = 0; n < 4; ++n) acc[m][n] = (fx4){0.f,0.f,0.f,0.f};

  __syncthreads();
  #pragma unroll
  for (int m = 0; m < 4; ++m){
    int row = wr*64 + m*16 + lr;
    bfx8 af[4];
    #pragma unroll
    for (int s = 0; s < 4; ++s)
      af[s] = *reinterpret_cast<const bfx8*>(lds + swzofs(row, s*32 + lh*8));
    #pragma unroll
    for (int n = 0; n < 4; ++n)
      #pragma unroll
      for (int s = 0; s < 4; ++s)
        acc[m][n] = __builtin_amdgcn_mfma_f32_16x16x32_bf16(af[s], bfr[n][s], acc[m][n], 0, 0, 0);
  }
  __syncthreads();

  for (int h = 0; h < 2; ++h){
    if (wr == h){
      #pragma unroll
      for (int m = 0; m < 4; ++m)
        #pragma unroll
        for (int n = 0; n < 4; ++n)
          #pragma unroll
          for (int i = 0; i < 4; ++i)
            Vt[(m*16 + lh*4 + i)*132 + wc*64 + n*16 + lr] = acc[m][n][i];
    }
    __syncthreads();
    {
      int r = t & 63, ch = t >> 6;
      int n = nb + h*64 + r;
      bool valid = n < M;
      int g = valid ? batch[n] : 0;
      #pragma unroll
      for (int i = 0; i < 8; ++i){
        int c = ch*32 + i*4;
        fx4 v = *reinterpret_cast<const fx4*>(&Vt[r*132 + c]);
        if (valid){
          fx4 u4 = *reinterpret_cast<const fx4*>(U2 + g*D + c);
          #pragma unroll
          for (int j = 0; j < 4; ++j){
            float vv = v[j] + u4[j];
            v[j] = vv;
            atomicAdd(&lsum[c+j], vv);
            atomicAdd(&lssq[c+j], vv*vv);
          }
          *reinterpret_cast<fx4*>(Xout + (size_t)n*D + c) = v;
        }
      }
    }
    __syncthreads();
  }
  if (t < 128){
    atomicAdd(stat_sum + t, lsum[t]);
    atomicAdd(stat_ssq + t, lssq[t]);
  }
}

// ---------------- node norm + per-graph sums ----------------
__global__ void node_norm(float* xio, const int* __restrict__ batch,
                          const float* __restrict__ ss, const float* __restrict__ alpha_p,
                          float* __restrict__ gsum, int M)
{
  __shared__ float part[128];
  const int t = threadIdx.x;
  const int nb = blockIdx.x * 128;
  int r = t & 127, ch = t >> 7;
  int n = nb + r;
  bool valid = n < M;
  float al = *alpha_p;
  int bg = valid ? batch[n] : -1;
  fx4 vals[16];
  #pragma unroll
  for (int i = 0; i < 16; ++i){
    int c = ch*64 + i*4;
    fx4 v = {0.f,0.f,0.f,0.f};
    if (valid){
      v = *reinterpret_cast<const fx4*>(xio + (size_t)n*D + c);
      fx4 s4 = *reinterpret_cast<const fx4*>(ss + c);
      fx4 b4 = *reinterpret_cast<const fx4*>(ss + 128 + c);
      #pragma unroll
      for (int j = 0; j < 4; ++j){
        float hh = v[j]*s4[j] + b4[j];
        v[j] = hh >= 0.f ? hh : al*hh;
      }
      *reinterpret_cast<fx4*>(xio + (size_t)n*D + c) = v;
    }
    vals[i] = v;
  }
  int hi = nb + 127 < M - 1 ? nb + 127 : M - 1;
  int g_lo = batch[nb];
  int g_hi = batch[hi];
  for (int g = g_lo; g <= g_hi; ++g){
    __syncthreads();
    if (t < 128) part[t] = 0.f;
    __syncthreads();
    if (valid && bg == g){
      #pragma unroll
      for (int i = 0; i < 16; ++i){
        int c = ch*64 + i*4;
        #pragma unroll
        for (int j = 0; j < 4; ++j) atomicAdd(&part[c+j], vals[i][j]);
      }
    }
    __syncthreads();
    if (t < 128) atomicAdd(gsum + g*D + t, part[t]);
  }
}

// ---------------- global model (single block) ----------------
__global__ void global_model(const float* __restrict__ u, const float* __restrict__ gsum,
                             const int* __restrict__ gcnt, const float* __restrict__ Wg,
                             const float* __restrict__ gamma, const float* __restrict__ beta,
                             const float* __restrict__ alpha_p, float* __restrict__ uout, int nG)
{
  __shared__ float z[32*256];
  __shared__ float zw[32*128];
  __shared__ float sc_[128], sh_[128];
  int t = threadIdx.x;
  for (int i = t; i < nG*256; i += 256){
    int g = i >> 8, c = i & 255;
    z[i] = (c < 128) ? u[g*128 + c]
                     : gsum[g*128 + (c - 128)] / fmaxf((float)gcnt[g], 1.f);
  }
  __syncthreads();
  for (int o = t; o < nG*128; o += 256){
    int g = o >> 7, j = o & 127;
    float s = 0.f;
    const float* zr = z + g*256;
    for (int k = 0; k < 256; ++k) s += zr[k] * Wg[k*128 + j];
    zw[o] = s;
  }
  __syncthreads();
  if (t < 128){
    float s = 0.f, q = 0.f;
    for (int g = 0; g < nG; ++g){ float v = zw[g*128 + t]; s += v; q += v*v; }
    float m = s / (float)nG;
    float var = q / (float)nG - m*m;
    float sc = gamma[t] * rsqrtf(var + EPS);
    sc_[t] = sc; sh_[t] = beta[t] - m*sc;
  }
  __syncthreads();
  float al = *alpha_p;
  for (int o = t; o < nG*128; o += 256){
    int j = o & 127;
    float v = zw[o]*sc_[j] + sh_[j];
    uout[o] = v >= 0.f ? v : al*v;
  }
}

// ---------------- host ----------------
extern "C" void kernel_launch(void* const* d_in, const int* in_sizes, int n_in,
                              void* d_out, int out_size, void* d_ws, size_t ws_size,
                              hipStream_t stream)
{
  (void)n_in; (void)out_size; (void)ws_size;
  const float* x    = (const float*)d_in[0];
  const int*   eidx = (const int*)d_in[1];
  const float* eatt = (const float*)d_in[2];
  const float* u    = (const float*)d_in[3];
  const int*   batch= (const int*)d_in[4];
  const float* We   = (const float*)d_in[5];
  const float* ge   = (const float*)d_in[6];
  const float* be   = (const float*)d_in[7];
  const float* ae   = (const float*)d_in[8];
  const float* Wn1  = (const float*)d_in[9];
  const float* gn1  = (const float*)d_in[10];
  const float* bn1  = (const float*)d_in[11];
  const float* an1  = (const float*)d_in[12];
  const float* Wn2  = (const float*)d_in[13];
  const float* gn2  = (const float*)d_in[14];
  const float* bn2  = (const float*)d_in[15];
  const float* an2  = (const float*)d_in[16];
  const float* Wg   = (const float*)d_in[17];
  const float* gg   = (const float*)d_in[18];
  const float* bg   = (const float*)d_in[19];
  const float* ag   = (const float*)d_in[20];

  const int nN = in_sizes[0] / D;       // 50000
  const int nE = in_sizes[2] / D;       // 600000
  const int nG = in_sizes[3] / D;       // 32
  const int* erow = eidx;
  const int* ecol = eidx + nE;

  float* out_x = (float*)d_out;
  float* out_e = out_x + (size_t)nN * D;
  float* out_u = out_e + (size_t)nE * D;

  // workspace carve-out (16B aligned chunks)
  char* wsb = (char*)d_ws;
  size_t off = 0;
  auto carve = [&](size_t bytes) -> void* {
    off = (off + 15) & ~(size_t)15;
    void* p = wsb + off;
    off += bytes;
    return p;
  };
  short* WT    = (short*)carve(5 * 16384 * 2);
  float* U1v   = (float*)carve((size_t)nG * D * 4);
  float* U2v   = (float*)carve((size_t)nG * D * 4);
  float* stats = (float*)carve(6 * 128 * 4);
  float* ss_e  = (float*)carve(256 * 4);
  float* ss_1  = (float*)carve(256 * 4);
  float* ss_2  = (float*)carve(256 * 4);
  int*   ncnt  = (int*)carve((size_t)nN * 4);
  float* gsum  = (float*)carve((size_t)nG * D * 4);
  int*   gcnt  = (int*)carve((size_t)nG * 4);
  short* P     = (short*)carve((size_t)nN * D * 2);
  short* Q     = (short*)carve((size_t)nN * D * 2);
  float* agg   = (float*)carve((size_t)nN * D * 4);

  float* ssum_e = stats;       float* ssq_e = stats + 128;
  float* ssum_1 = stats + 256; float* ssq_1 = stats + 384;
  float* ssum_2 = stats + 512; float* ssq_2 = stats + 640;

  hipMemsetAsync(stats, 0, 6 * 128 * 4, stream);
  hipMemsetAsync(ncnt, 0, (size_t)nN * 4, stream);
  hipMemsetAsync(gsum, 0, (size_t)nG * D * 4, stream);
  hipMemsetAsync(gcnt, 0, (size_t)nG * 4, stream);
  hipMemsetAsync(agg, 0, (size_t)nN * D * 4, stream);

  const int gE = (nE + 127) / 128;
  const int gN = (nN + 127) / 128;

  prep_w<<<320, 256, 0, stream>>>(We, Wn1, Wn2, WT);
  prep_u<<<32, 256, 0, stream>>>(u, We, Wn2, U1v, U2v);
  counts_k<<<(nE + nN + 255) / 256, 256, 0, stream>>>(erow, batch, ncnt, gcnt, nE, nN);

  gemm_xw<<<gN, 256, 0, stream>>>(x, WT,           P, nN);   // P = x @ We1
  gemm_xw<<<gN, 256, 0, stream>>>(x, WT + 16384,   Q, nN);   // Q = x @ Wn1_top

  edge_pass<0><<<gE, 256, 0, stream>>>(eatt, out_e, erow, ecol, batch, P, U1v,
                                       WT + 2*16384, nullptr, nullptr, nullptr, nullptr,
                                       ssum_e, ssq_e, nullptr, nE);
  bn_fin<<<1, 128, 0, stream>>>(ssum_e, ssq_e, ge, be, (float)nE, ss_e);

  edge_pass<1><<<gE, 256, 0, stream>>>(nullptr, out_e, erow, ecol, batch, Q, nullptr,
                                       WT + 3*16384, ss_e, ae, nullptr, nullptr,
                                       ssum_1, ssq_1, nullptr, nE);
  bn_fin<<<1, 128, 0, stream>>>(ssum_1, ssq_1, gn1, bn1, (float)nE, ss_1);

  edge_pass<2><<<gE, 256, 0, stream>>>(nullptr, out_e, erow, ecol, batch, Q, nullptr,
                                       WT + 3*16384, nullptr, nullptr, ss_1, an1,
                                       nullptr, nullptr, agg, nE);

  node2_pass<<<gN, 256, 0, stream>>>(agg, ncnt, batch, U2v, WT + 4*16384, out_x,
                                     ssum_2, ssq_2, nN);
  bn_fin<<<1, 128, 0, stream>>>(ssum_2, ssq_2, gn2, bn2, (float)nN, ss_2);

  node_norm<<<gN, 256, 0, stream>>>(out_x, batch, ss_2, an2, gsum, nN);

  global_model<<<1, 256, 0, stream>>>(u, gsum, gcnt, Wg, gg, bg, ag, out_u, nG);
}